// Round 7
// baseline (181.371 us; speedup 1.0000x reference)
//
#include <hip/hip_runtime.h>
#include <hip/hip_fp16.h>
#include <stdint.h>

// LightGCNConv: out[row] += x[col] * edge_weight[e]
// x:[N,64] f32, edge_index:[2,E] int32, edge_weight:[E] f32, out:[N,64] f32.
//
// Pipeline (v7 — occupancy-fixed bucket_acc, packed 5B seg entries):
//  1) prep: merged {edge binning | x->bf16 convert}. Per block (CHUNK=4096):
//     LDS hist+rank -> exclusive scan -> bucket-SORTED placement in LDS ->
//     wave-coalesced sweep stores (v6: killed the 64-partial-line scatter,
//     prep 68.6 -> <55us). v7: entries packed to 4B (col|fp16w) + 1B rl
//     at prep time (CSR tile already used fp16 w -> identical numerics),
//     cutting seg store/load bytes ~38%.
//  2) bucket_acc: RB=64 rows/bucket, 256 thr -> grid 1563 (~6 blocks/CU,
//     8/CU cap; v6: RB=128/512thr gave grid 782 = 3.05/CU, 46% occupancy
//     on a latency-bound gather stream). Seg -> LDS padded-CSR (pure copy,
//     native int cursor atomics) -> per-wave REGISTER accumulation of 16
//     rows, 8-deep pipelined bf16 gathers -> coalesced nontemporal stores.

typedef unsigned long long ull;
typedef int   v4i __attribute__((ext_vector_type(4)));
typedef float v4f __attribute__((ext_vector_type(4)));
typedef unsigned char uchar;

#define RB      64       // rows per bucket
#define CAP     1280     // entries per bucket segment; mean 1024 (+8 sigma)
#define CHUNK   4096     // edges per bin block (512 thr x 8)
#define EPT     8        // edges per thread in prep
#define SLOTS   48       // padded-CSR slots per row (deg ~Poisson(16))
#define BPAD    16       // bcnt stride in ints (64B: one counter per line)
#define OVF_CAP 65536
#define NBP     2048     // padded bucket count (N <= 131072 -> NB <= 2048)

__device__ __forceinline__ unsigned short f2bf(float f) {
    union { float f; unsigned int u; } c;
    c.f = f;
    unsigned int lsb = (c.u >> 16) & 1u;
    c.u += 0x7fffu + lsb;
    return (unsigned short)(c.u >> 16);
}
__device__ __forceinline__ float bf2f(unsigned short u) {
    union { unsigned int u; float f; } c;
    c.u = ((unsigned int)u) << 16;
    return c.f;
}
__device__ __forceinline__ unsigned pack_cw(int col, float w) {
    unsigned hb = __half_as_ushort(__float2half(w));
    return (((unsigned)col) << 15) | (hb >> 1);
}
__device__ __forceinline__ float unpack_w(unsigned v) {
    return __half2float(__ushort_as_half((unsigned short)((v & 0x7fffu) << 1)));
}

// ---------- phase 1 (merged): sorted edge binning | x->bf16 convert ------
__global__ __launch_bounds__(512) void prep(
    const int* __restrict__ ei, const float* __restrict__ ew,
    int* __restrict__ bcnt, unsigned* __restrict__ s4g,
    uchar* __restrict__ srg,
    int* __restrict__ ovf_cnt, int3* __restrict__ ovf, int E, int NB,
    int nbin, const float* __restrict__ x, unsigned short* __restrict__ xb,
    int n4)
{
    __shared__ int      hist[NBP];      // 8 KB
    __shared__ int      lstart[NBP];    // 8 KB
    __shared__ int      gbase[NBP];     // 8 KB
    __shared__ int      wsum[8];
    __shared__ unsigned s4_l[CHUNK];    // 16 KB
    __shared__ uchar    sr_l[CHUNK];    // 4 KB
    __shared__ unsigned gpos[CHUNK];    // 16 KB
    int t = threadIdx.x;

    if ((int)blockIdx.x >= nbin) {
        // ---- convert part: 4096 v4f per block ----
        int i0 = ((int)blockIdx.x - nbin) * 4096 + t;
#pragma unroll
        for (int k = 0; k < 8; ++k) {
            int i = i0 + k * 512;
            if (i < n4) {
                v4f v = ((const v4f*)x)[i];
                ushort4 o;
                o.x = f2bf(v.x); o.y = f2bf(v.y);
                o.z = f2bf(v.z); o.w = f2bf(v.w);
                ((ushort4*)xb)[i] = o;
            }
        }
        return;
    }

    // ---- bin part ----
    for (int i = t; i < NBP; i += 512) hist[i] = 0;
    __syncthreads();

    int e0   = blockIdx.x * CHUNK;
    int nval = E - e0; if (nval > CHUNK) nval = CHUNK;
    bool al4 = ((E & 3) == 0);

    int      rk[EPT];     // rank within (block,bucket)
    unsigned br[EPT];     // bkt<<6 | rl
    unsigned p4[EPT];     // col<<15 | fp16w>>1
    bool     vd[EPT];
#pragma unroll
    for (int j = 0; j < EPT / 4; ++j) {
        int eb = e0 + (j * 512 + t) * 4;
        v4i r4, c4; v4f w4;
        if (al4 && eb + 3 < E) {
            r4 = *(const v4i*)(ei + eb);
            c4 = *(const v4i*)(ei + E + eb);
            w4 = *(const v4f*)(ew + eb);
        } else {
#pragma unroll
            for (int u = 0; u < 4; ++u) {
                int e = eb + u;
                r4[u] = e < E ? ei[e] : 0;
                c4[u] = e < E ? ei[E + e] : 0;
                w4[u] = e < E ? ew[e] : 0.f;
            }
        }
#pragma unroll
        for (int u = 0; u < 4; ++u) {
            int idx = j * 4 + u;
            int e = eb + u;
            vd[idx] = e < E;
            int bkt = r4[u] >> 6;
            rk[idx] = vd[idx] ? atomicAdd(&hist[bkt], 1) : 0;  // LDS native
            br[idx] = (unsigned)((bkt << 6) | (r4[u] & (RB - 1)));
            p4[idx] = pack_cw(c4[u], w4[u]);
        }
    }
    __syncthreads();

    // ---- exclusive scan hist[0..NBP): 4/thread + wave + block ----
    {
        int h0 = hist[4 * t],     h1 = hist[4 * t + 1];
        int h2 = hist[4 * t + 2], h3 = hist[4 * t + 3];
        int ps = h0 + h1 + h2 + h3;
        int lane = t & 63, wid = t >> 6;
        int s = ps;
#pragma unroll
        for (int off = 1; off < 64; off <<= 1) {
            int o = __shfl_up(s, off);
            if (lane >= off) s += o;
        }
        if (lane == 63) wsum[wid] = s;
        __syncthreads();
        if (t < 8) {
            int v = wsum[t];
            int s2 = v;
#pragma unroll
            for (int off = 1; off < 8; off <<= 1) {
                int o = __shfl_up(s2, off);
                if (t >= off) s2 += o;
            }
            wsum[t] = s2 - v;    // exclusive wave offset
        }
        __syncthreads();
        int excl = s - ps + wsum[wid];
        lstart[4 * t]     = excl;
        lstart[4 * t + 1] = excl + h0;
        lstart[4 * t + 2] = excl + h0 + h1;
        lstart[4 * t + 3] = excl + h0 + h1 + h2;
    }

    // ---- global reservations: one atomic per (block,bucket), padded ----
    for (int i = t; i < NB; i += 512) {
        int h = hist[i];
        gbase[i] = h ? atomicAdd(&bcnt[i * BPAD], h) : 0;
    }
    __syncthreads();

    // ---- pass 2: place sorted in LDS + precompute global pos ----
#pragma unroll
    for (int j = 0; j < EPT; ++j) {
        if (!vd[j]) continue;
        int bkt = (int)(br[j] >> 6);
        int lp  = lstart[bkt] + rk[j];
        s4_l[lp] = p4[j];
        sr_l[lp] = (uchar)(br[j] & (RB - 1));
        int loc = gbase[bkt] + rk[j];
        if (loc < CAP) {
            gpos[lp] = (unsigned)(bkt * CAP + loc);
        } else {
            gpos[lp] = 0xFFFFFFFFu;
            int o = atomicAdd(ovf_cnt, 1);
            if (o < OVF_CAP)
                ovf[o] = make_int3(bkt * RB + (int)(br[j] & (RB - 1)),
                                   (int)(p4[j] >> 15),
                                   __float_as_int(unpack_w(p4[j])));
        }
    }
    __syncthreads();

    // ---- pass 3: wave-coalesced sweep stores (4B + 1B arrays) ----
    for (int i = t; i < nval; i += 512) {
        unsigned gp = gpos[i];
        if (gp != 0xFFFFFFFFu) {
            s4g[gp] = s4_l[i];
            srg[gp] = sr_l[i];
        }
    }
}

// ---------- phase 2: segment -> LDS padded CSR -> register acc -> out ----
// 256 thr (4 waves), ~12.5 KB LDS, 8 blocks/CU cap, grid ~1563.
template <bool BF>
__global__ __launch_bounds__(256, 8) void bucket_acc(
    const void* __restrict__ xv, const unsigned* __restrict__ s4g,
    const uchar* __restrict__ srg,
    const int* __restrict__ bcnt, float* __restrict__ out,
    int* __restrict__ ovf_cnt, int3* __restrict__ ovf, int N)
{
    __shared__ int      cur[RB];
    __shared__ unsigned tile[RB * SLOTS];   // 12 KB packed col|fp16w
    int t = threadIdx.x;
    int g = blockIdx.x;
    if (t < RB) cur[t] = 0;
    __syncthreads();

    int c = bcnt[g * BPAD];
    if (c > CAP) c = CAP;
    const unsigned* b4 = s4g + (size_t)g * CAP;
    const uchar*    br = srg + (size_t)g * CAP;

    // build LDS CSR: coalesced 4B+1B reads, LDS cursor atomic, LDS write
    for (int i = t; i < c; i += 256) {
        unsigned p4 = b4[i];
        int rl = br[i];
        int pos = atomicAdd(&cur[rl], 1);          // native LDS int atomic
        if (pos < SLOTS) {
            tile[rl * SLOTS + pos] = p4;
        } else {
            int o = atomicAdd(ovf_cnt, 1);
            if (o < OVF_CAP)
                ovf[o] = make_int3(g * RB + rl, (int)(p4 >> 15),
                                   __float_as_int(unpack_w(p4)));
        }
    }
    __syncthreads();

    // register accumulation: each wave handles 16 rows, 8-deep gathers
    int wid  = t >> 6;
    int lane = t & 63;
    const unsigned short* xh = (const unsigned short*)xv;
    const float*          xf = (const float*)xv;

    for (int k = 0; k < 16; ++k) {
        int r   = wid * 16 + k;
        int row = g * RB + r;
        if (row >= N) break;
        int cc = cur[r];
        if (cc > SLOTS) cc = SLOTS;
        const unsigned* tb = &tile[r * SLOTS];

        float acc = 0.0f;
        int p = 0;
        for (; p + 8 <= cc; p += 8) {
            unsigned a[8]; float xr[8];
#pragma unroll
            for (int i = 0; i < 8; ++i) a[i] = tb[p + i];   // LDS broadcast
#pragma unroll
            for (int i = 0; i < 8; ++i) {
                size_t off = (((size_t)(a[i] >> 15)) << 6) + lane;
                xr[i] = BF ? bf2f(xh[off]) : xf[off];
            }
#pragma unroll
            for (int i = 0; i < 8; ++i)
                acc = fmaf(xr[i], unpack_w(a[i]), acc);
        }
        if (p < cc) {   // masked 8-group tail (cc >= 1 here)
            unsigned a[8]; float xr[8], w[8];
#pragma unroll
            for (int i = 0; i < 8; ++i) {
                int q = p + i;
                bool valid = q < cc;
                if (!valid) q = cc - 1;
                a[i] = tb[q];
                w[i] = valid ? unpack_w(a[i]) : 0.0f;
            }
#pragma unroll
            for (int i = 0; i < 8; ++i) {
                size_t off = (((size_t)(a[i] >> 15)) << 6) + lane;
                xr[i] = BF ? bf2f(xh[off]) : xf[off];
            }
#pragma unroll
            for (int i = 0; i < 8; ++i) acc = fmaf(xr[i], w[i], acc);
        }
        __builtin_nontemporal_store(acc, out + (((size_t)row) << 6) + lane);
    }
}

// ---------- overflow fixup (normally 0 edges) ----------
template <bool BF>
__global__ __launch_bounds__(256) void ovf_apply(
    const void* __restrict__ xv, const int* __restrict__ ovf_cnt,
    const int3* __restrict__ ovf, float* __restrict__ out)
{
    int n = *ovf_cnt;
    if (n > OVF_CAP) n = OVF_CAP;
    int wid  = (blockIdx.x * 256 + threadIdx.x) >> 6;
    int lane = threadIdx.x & 63;
    int nw   = gridDim.x * 4;
    for (int o = wid; o < n; o += nw) {
        int3 tt = ovf[o];
        float w = __int_as_float(tt.z);
        size_t off = (((size_t)tt.y) << 6) + lane;
        float x = BF ? bf2f(((const unsigned short*)xv)[off])
                     : ((const float*)xv)[off];
        atomicAdd(&out[(((size_t)tt.x) << 6) + lane], x * w);
    }
}

// ---------- fallback: direct atomic scatter ----------
__global__ __launch_bounds__(256) void scatter_edges(
    const float* __restrict__ x, const int* __restrict__ ei,
    const float* __restrict__ ew, float* __restrict__ out, int E)
{
    long long idx = (long long)blockIdx.x * 256 + threadIdx.x;
    int e = (int)(idx >> 4);
    if (e >= E) return;
    int j = (int)(idx & 15);
    int row = ei[e];
    int col = ei[E + e];
    float w = ew[e];
    v4f v = *(const v4f*)(x + (((size_t)col) << 6) + (j << 2));
    float* op = out + (((size_t)row) << 6) + (j << 2);
    atomicAdd(op + 0, v.x * w);
    atomicAdd(op + 1, v.y * w);
    atomicAdd(op + 2, v.z * w);
    atomicAdd(op + 3, v.w * w);
}

extern "C" void kernel_launch(void* const* d_in, const int* in_sizes, int n_in,
                              void* d_out, int out_size, void* d_ws, size_t ws_size,
                              hipStream_t stream) {
    const float* x  = (const float*)d_in[0];
    const int*   ei = (const int*)d_in[1];
    const float* ew = (const float*)d_in[2];
    float*       out = (float*)d_out;

    int E = in_sizes[2];
    int N = out_size / 64;
    int NB = (N + RB - 1) / RB;

    // ws (ints): bcnt[NB*BPAD] | ovf_cnt | pad | ovf[3*OVF] | [xb N*32] |
    //            s4g[NB*CAP] | srg[NB*CAP/4]
    size_t ovf_base  = (size_t)NB * BPAD + 2;
    size_t xb_base   = (ovf_base + 3 * (size_t)OVF_CAP + 3) & ~(size_t)3;
    size_t xb_ints   = (size_t)N * 32;
    size_t s4_ints   = (size_t)NB * CAP;
    size_t sr_ints   = ((size_t)NB * CAP + 3) / 4;

    size_t s4_base_bf  = xb_base + xb_ints;
    size_t sr_base_bf  = s4_base_bf + s4_ints;
    size_t need_bf     = (sr_base_bf + sr_ints) * 4;

    size_t s4_base_f   = xb_base;
    size_t sr_base_f   = s4_base_f + s4_ints;
    size_t need_f      = (sr_base_f + sr_ints) * 4;

    int nbin  = (E + CHUNK - 1) / CHUNK;
    int n4    = (N * 64) / 4;
    int nconv = (n4 + 4095) / 4096;

    if ((ws_size >= need_bf || ws_size >= need_f) && N <= (1 << 17)) {
        bool use_bf = ws_size >= need_bf;
        int* w32 = (int*)d_ws;
        int* bcnt = w32;
        int* ovf_cnt = w32 + NB * BPAD;
        int3* ovf = (int3*)(w32 + ovf_base);
        unsigned short* xb = (unsigned short*)(w32 + xb_base);
        unsigned* s4g = (unsigned*)(w32 + (use_bf ? s4_base_bf : s4_base_f));
        uchar*    srg = (uchar*)(w32 + (use_bf ? sr_base_bf : sr_base_f));

        (void)hipMemsetAsync(w32, 0, ((size_t)NB * BPAD + 2) * sizeof(int),
                             stream);

        if (use_bf) {
            prep<<<nbin + nconv, 512, 0, stream>>>(
                ei, ew, bcnt, s4g, srg, ovf_cnt, ovf, E, NB, nbin, x, xb, n4);
            bucket_acc<true><<<NB, 256, 0, stream>>>(
                xb, s4g, srg, bcnt, out, ovf_cnt, ovf, N);
            ovf_apply<true><<<64, 256, 0, stream>>>(xb, ovf_cnt, ovf, out);
        } else {
            prep<<<nbin, 512, 0, stream>>>(
                ei, ew, bcnt, s4g, srg, ovf_cnt, ovf, E, NB, nbin, x, xb, 0);
            bucket_acc<false><<<NB, 256, 0, stream>>>(
                x, s4g, srg, bcnt, out, ovf_cnt, ovf, N);
            ovf_apply<false><<<64, 256, 0, stream>>>(x, ovf_cnt, ovf, out);
        }
    } else {
        (void)hipMemsetAsync(out, 0, (size_t)out_size * sizeof(float), stream);
        long long threads = (long long)E * 16;
        scatter_edges<<<(int)((threads + 255) / 256), 256, 0, stream>>>(
            x, ei, ew, out, E);
    }
}

// Round 8
// 180.590 us; speedup vs baseline: 1.0043x; 1.0043x over previous
//
#include <hip/hip_runtime.h>
#include <hip/hip_fp16.h>
#include <stdint.h>

// LightGCNConv: out[row] += x[col] * edge_weight[e]
// x:[N,64] f32, edge_index:[2,E] int32, edge_weight:[E] f32, out:[N,64] f32.
//
// Pipeline (v8 — prep occupancy fix: 52KB LDS, fused reserve+scan):
//  1) prep: merged {edge binning | x->bf16 convert}. Per block (CHUNK=4096):
//     LDS hist+rank -> {global reservations || exclusive scan} in ONE
//     barrier region -> bucket-sorted placement in LDS (4B pack + 1B rl +
//     2B bkt) -> wave-coalesced sweep stores with on-the-fly global pos
//     (gbase[bkt] + i - lstart[bkt]). v7's 16KB gpos array dropped:
//     LDS 60.5->52KB = 3 blocks/CU (v7: 2 blocks/CU, 31% occupancy,
//     VALUBusy 3.3% -> latency-bound barrier chain).
//  2) bucket_acc: RB=64 rows/bucket, 256 thr, grid 1563 (~6 blocks/CU).
//     Seg -> LDS padded-CSR (pure copy, native int cursor atomics) ->
//     per-wave REGISTER accumulation of 16 rows, 8-deep pipelined bf16
//     gathers -> coalesced nontemporal stores. Near random-line roofline
//     (~3.1 TB/s line traffic on 205MB gather floor).

typedef unsigned long long ull;
typedef int   v4i __attribute__((ext_vector_type(4)));
typedef float v4f __attribute__((ext_vector_type(4)));
typedef unsigned char  uchar;
typedef unsigned short ushortt;

#define RB      64       // rows per bucket
#define CAP     1280     // entries per bucket segment; mean 1024 (+8 sigma)
#define CHUNK   4096     // edges per bin block (512 thr x 8)
#define EPT     8        // edges per thread in prep
#define SLOTS   48       // padded-CSR slots per row (deg ~Poisson(16))
#define BPAD    16       // bcnt stride in ints (64B: one counter per line)
#define OVF_CAP 65536
#define NBP     2048     // padded bucket count (N <= 131072 -> NB <= 2048)

__device__ __forceinline__ unsigned short f2bf(float f) {
    union { float f; unsigned int u; } c;
    c.f = f;
    unsigned int lsb = (c.u >> 16) & 1u;
    c.u += 0x7fffu + lsb;
    return (unsigned short)(c.u >> 16);
}
__device__ __forceinline__ float bf2f(unsigned short u) {
    union { unsigned int u; float f; } c;
    c.u = ((unsigned int)u) << 16;
    return c.f;
}
__device__ __forceinline__ unsigned pack_cw(int col, float w) {
    unsigned hb = __half_as_ushort(__float2half(w));
    return (((unsigned)col) << 15) | (hb >> 1);
}
__device__ __forceinline__ float unpack_w(unsigned v) {
    return __half2float(__ushort_as_half((unsigned short)((v & 0x7fffu) << 1)));
}

// ---------- phase 1 (merged): sorted edge binning | x->bf16 convert ------
__global__ __launch_bounds__(512) void prep(
    const int* __restrict__ ei, const float* __restrict__ ew,
    int* __restrict__ bcnt, unsigned* __restrict__ s4g,
    uchar* __restrict__ srg,
    int* __restrict__ ovf_cnt, int3* __restrict__ ovf, int E, int NB,
    int nbin, const float* __restrict__ x, unsigned short* __restrict__ xb,
    int n4)
{
    __shared__ int      hist[NBP];      // 8 KB
    __shared__ int      lstart[NBP];    // 8 KB
    __shared__ int      gbase[NBP];     // 8 KB
    __shared__ int      wsum[8];
    __shared__ unsigned s4_l[CHUNK];    // 16 KB
    __shared__ uchar    sr_l[CHUNK];    // 4 KB
    __shared__ ushortt  bk_l[CHUNK];    // 8 KB   => total 52 KB, 3 blk/CU
    int t = threadIdx.x;

    if ((int)blockIdx.x >= nbin) {
        // ---- convert part: 4096 v4f per block ----
        int i0 = ((int)blockIdx.x - nbin) * 4096 + t;
#pragma unroll
        for (int k = 0; k < 8; ++k) {
            int i = i0 + k * 512;
            if (i < n4) {
                v4f v = ((const v4f*)x)[i];
                ushort4 o;
                o.x = f2bf(v.x); o.y = f2bf(v.y);
                o.z = f2bf(v.z); o.w = f2bf(v.w);
                ((ushort4*)xb)[i] = o;
            }
        }
        return;
    }

    // ---- bin part ----
    for (int i = t; i < NBP; i += 512) hist[i] = 0;
    __syncthreads();

    int e0   = blockIdx.x * CHUNK;
    int nval = E - e0; if (nval > CHUNK) nval = CHUNK;
    bool al4 = ((E & 3) == 0);

    int      rk[EPT];     // rank within (block,bucket)
    unsigned br[EPT];     // bkt<<6 | rl
    unsigned p4[EPT];     // col<<15 | fp16w>>1
    bool     vd[EPT];
#pragma unroll
    for (int j = 0; j < EPT / 4; ++j) {
        int eb = e0 + (j * 512 + t) * 4;
        v4i r4, c4; v4f w4;
        if (al4 && eb + 3 < E) {
            r4 = *(const v4i*)(ei + eb);
            c4 = *(const v4i*)(ei + E + eb);
            w4 = *(const v4f*)(ew + eb);
        } else {
#pragma unroll
            for (int u = 0; u < 4; ++u) {
                int e = eb + u;
                r4[u] = e < E ? ei[e] : 0;
                c4[u] = e < E ? ei[E + e] : 0;
                w4[u] = e < E ? ew[e] : 0.f;
            }
        }
#pragma unroll
        for (int u = 0; u < 4; ++u) {
            int idx = j * 4 + u;
            int e = eb + u;
            vd[idx] = e < E;
            int bkt = r4[u] >> 6;
            rk[idx] = vd[idx] ? atomicAdd(&hist[bkt], 1) : 0;  // LDS native
            br[idx] = (unsigned)((bkt << 6) | (r4[u] & (RB - 1)));
            p4[idx] = pack_cw(c4[u], w4[u]);
        }
    }
    __syncthreads();

    // ---- global reservations (latency hidden under scan below) ----
    for (int i = t; i < NB; i += 512) {
        int h = hist[i];
        gbase[i] = h ? atomicAdd(&bcnt[i * BPAD], h) : 0;
    }
    // ---- exclusive scan hist[0..NBP) -> lstart: 4/thread + wave + block
    {
        int h0 = hist[4 * t],     h1 = hist[4 * t + 1];
        int h2 = hist[4 * t + 2], h3 = hist[4 * t + 3];
        int ps = h0 + h1 + h2 + h3;
        int lane = t & 63, wid = t >> 6;
        int s = ps;
#pragma unroll
        for (int off = 1; off < 64; off <<= 1) {
            int o = __shfl_up(s, off);
            if (lane >= off) s += o;
        }
        if (lane == 63) wsum[wid] = s;
        __syncthreads();
        if (t < 8) {
            int v = wsum[t];
            int s2 = v;
#pragma unroll
            for (int off = 1; off < 8; off <<= 1) {
                int o = __shfl_up(s2, off);
                if (t >= off) s2 += o;
            }
            wsum[t] = s2 - v;    // exclusive wave offset
        }
        __syncthreads();
        int excl = s - ps + wsum[wid];
        lstart[4 * t]     = excl;
        lstart[4 * t + 1] = excl + h0;
        lstart[4 * t + 2] = excl + h0 + h1;
        lstart[4 * t + 3] = excl + h0 + h1 + h2;
    }
    __syncthreads();

    // ---- pass 2: place sorted in LDS ----
#pragma unroll
    for (int j = 0; j < EPT; ++j) {
        if (!vd[j]) continue;
        int bkt = (int)(br[j] >> 6);
        int lp  = lstart[bkt] + rk[j];
        s4_l[lp] = p4[j];
        sr_l[lp] = (uchar)(br[j] & (RB - 1));
        bk_l[lp] = (ushortt)bkt;
    }
    __syncthreads();

    // ---- pass 3: wave-coalesced sweep stores, on-the-fly global pos ----
    for (int i = t; i < nval; i += 512) {
        int bkt = (int)bk_l[i];
        int loc = gbase[bkt] + (i - lstart[bkt]);
        unsigned p = s4_l[i];
        if (loc < CAP) {
            size_t gp = (size_t)bkt * CAP + loc;
            s4g[gp] = p;
            srg[gp] = sr_l[i];
        } else {
            int o = atomicAdd(ovf_cnt, 1);
            if (o < OVF_CAP)
                ovf[o] = make_int3(bkt * RB + (int)sr_l[i],
                                   (int)(p >> 15),
                                   __float_as_int(unpack_w(p)));
        }
    }
}

// ---------- phase 2: segment -> LDS padded CSR -> register acc -> out ----
// 256 thr (4 waves), ~12.5 KB LDS, 8 blocks/CU cap, grid ~1563.
template <bool BF>
__global__ __launch_bounds__(256, 8) void bucket_acc(
    const void* __restrict__ xv, const unsigned* __restrict__ s4g,
    const uchar* __restrict__ srg,
    const int* __restrict__ bcnt, float* __restrict__ out,
    int* __restrict__ ovf_cnt, int3* __restrict__ ovf, int N)
{
    __shared__ int      cur[RB];
    __shared__ unsigned tile[RB * SLOTS];   // 12 KB packed col|fp16w
    int t = threadIdx.x;
    int g = blockIdx.x;
    if (t < RB) cur[t] = 0;
    __syncthreads();

    int c = bcnt[g * BPAD];
    if (c > CAP) c = CAP;
    const unsigned* b4 = s4g + (size_t)g * CAP;
    const uchar*    br = srg + (size_t)g * CAP;

    // build LDS CSR: coalesced 4B+1B reads, LDS cursor atomic, LDS write
    for (int i = t; i < c; i += 256) {
        unsigned p4 = b4[i];
        int rl = br[i];
        int pos = atomicAdd(&cur[rl], 1);          // native LDS int atomic
        if (pos < SLOTS) {
            tile[rl * SLOTS + pos] = p4;
        } else {
            int o = atomicAdd(ovf_cnt, 1);
            if (o < OVF_CAP)
                ovf[o] = make_int3(g * RB + rl, (int)(p4 >> 15),
                                   __float_as_int(unpack_w(p4)));
        }
    }
    __syncthreads();

    // register accumulation: each wave handles 16 rows, 8-deep gathers
    int wid  = t >> 6;
    int lane = t & 63;
    const unsigned short* xh = (const unsigned short*)xv;
    const float*          xf = (const float*)xv;

    for (int k = 0; k < 16; ++k) {
        int r   = wid * 16 + k;
        int row = g * RB + r;
        if (row >= N) break;
        int cc = cur[r];
        if (cc > SLOTS) cc = SLOTS;
        const unsigned* tb = &tile[r * SLOTS];

        float acc = 0.0f;
        int p = 0;
        for (; p + 8 <= cc; p += 8) {
            unsigned a[8]; float xr[8];
#pragma unroll
            for (int i = 0; i < 8; ++i) a[i] = tb[p + i];   // LDS broadcast
#pragma unroll
            for (int i = 0; i < 8; ++i) {
                size_t off = (((size_t)(a[i] >> 15)) << 6) + lane;
                xr[i] = BF ? bf2f(xh[off]) : xf[off];
            }
#pragma unroll
            for (int i = 0; i < 8; ++i)
                acc = fmaf(xr[i], unpack_w(a[i]), acc);
        }
        if (p < cc) {   // masked 8-group tail (cc >= 1 here)
            unsigned a[8]; float xr[8], w[8];
#pragma unroll
            for (int i = 0; i < 8; ++i) {
                int q = p + i;
                bool valid = q < cc;
                if (!valid) q = cc - 1;
                a[i] = tb[q];
                w[i] = valid ? unpack_w(a[i]) : 0.0f;
            }
#pragma unroll
            for (int i = 0; i < 8; ++i) {
                size_t off = (((size_t)(a[i] >> 15)) << 6) + lane;
                xr[i] = BF ? bf2f(xh[off]) : xf[off];
            }
#pragma unroll
            for (int i = 0; i < 8; ++i) acc = fmaf(xr[i], w[i], acc);
        }
        __builtin_nontemporal_store(acc, out + (((size_t)row) << 6) + lane);
    }
}

// ---------- overflow fixup (normally 0 edges) ----------
template <bool BF>
__global__ __launch_bounds__(256) void ovf_apply(
    const void* __restrict__ xv, const int* __restrict__ ovf_cnt,
    const int3* __restrict__ ovf, float* __restrict__ out)
{
    int n = *ovf_cnt;
    if (n > OVF_CAP) n = OVF_CAP;
    int wid  = (blockIdx.x * 256 + threadIdx.x) >> 6;
    int lane = threadIdx.x & 63;
    int nw   = gridDim.x * 4;
    for (int o = wid; o < n; o += nw) {
        int3 tt = ovf[o];
        float w = __int_as_float(tt.z);
        size_t off = (((size_t)tt.y) << 6) + lane;
        float x = BF ? bf2f(((const unsigned short*)xv)[off])
                     : ((const float*)xv)[off];
        atomicAdd(&out[(((size_t)tt.x) << 6) + lane], x * w);
    }
}

// ---------- fallback: direct atomic scatter ----------
__global__ __launch_bounds__(256) void scatter_edges(
    const float* __restrict__ x, const int* __restrict__ ei,
    const float* __restrict__ ew, float* __restrict__ out, int E)
{
    long long idx = (long long)blockIdx.x * 256 + threadIdx.x;
    int e = (int)(idx >> 4);
    if (e >= E) return;
    int j = (int)(idx & 15);
    int row = ei[e];
    int col = ei[E + e];
    float w = ew[e];
    v4f v = *(const v4f*)(x + (((size_t)col) << 6) + (j << 2));
    float* op = out + (((size_t)row) << 6) + (j << 2);
    atomicAdd(op + 0, v.x * w);
    atomicAdd(op + 1, v.y * w);
    atomicAdd(op + 2, v.z * w);
    atomicAdd(op + 3, v.w * w);
}

extern "C" void kernel_launch(void* const* d_in, const int* in_sizes, int n_in,
                              void* d_out, int out_size, void* d_ws, size_t ws_size,
                              hipStream_t stream) {
    const float* x  = (const float*)d_in[0];
    const int*   ei = (const int*)d_in[1];
    const float* ew = (const float*)d_in[2];
    float*       out = (float*)d_out;

    int E = in_sizes[2];
    int N = out_size / 64;
    int NB = (N + RB - 1) / RB;

    // ws (ints): bcnt[NB*BPAD] | ovf_cnt | pad | ovf[3*OVF] | [xb N*32] |
    //            s4g[NB*CAP] | srg[NB*CAP/4]
    size_t ovf_base  = (size_t)NB * BPAD + 2;
    size_t xb_base   = (ovf_base + 3 * (size_t)OVF_CAP + 3) & ~(size_t)3;
    size_t xb_ints   = (size_t)N * 32;
    size_t s4_ints   = (size_t)NB * CAP;
    size_t sr_ints   = ((size_t)NB * CAP + 3) / 4;

    size_t s4_base_bf  = xb_base + xb_ints;
    size_t sr_base_bf  = s4_base_bf + s4_ints;
    size_t need_bf     = (sr_base_bf + sr_ints) * 4;

    size_t s4_base_f   = xb_base;
    size_t sr_base_f   = s4_base_f + s4_ints;
    size_t need_f      = (sr_base_f + sr_ints) * 4;

    int nbin  = (E + CHUNK - 1) / CHUNK;
    int n4    = (N * 64) / 4;
    int nconv = (n4 + 4095) / 4096;

    if ((ws_size >= need_bf || ws_size >= need_f) && N <= (1 << 17)) {
        bool use_bf = ws_size >= need_bf;
        int* w32 = (int*)d_ws;
        int* bcnt = w32;
        int* ovf_cnt = w32 + NB * BPAD;
        int3* ovf = (int3*)(w32 + ovf_base);
        unsigned short* xb = (unsigned short*)(w32 + xb_base);
        unsigned* s4g = (unsigned*)(w32 + (use_bf ? s4_base_bf : s4_base_f));
        uchar*    srg = (uchar*)(w32 + (use_bf ? sr_base_bf : sr_base_f));

        (void)hipMemsetAsync(w32, 0, ((size_t)NB * BPAD + 2) * sizeof(int),
                             stream);

        if (use_bf) {
            prep<<<nbin + nconv, 512, 0, stream>>>(
                ei, ew, bcnt, s4g, srg, ovf_cnt, ovf, E, NB, nbin, x, xb, n4);
            bucket_acc<true><<<NB, 256, 0, stream>>>(
                xb, s4g, srg, bcnt, out, ovf_cnt, ovf, N);
            ovf_apply<true><<<64, 256, 0, stream>>>(xb, ovf_cnt, ovf, out);
        } else {
            prep<<<nbin, 512, 0, stream>>>(
                ei, ew, bcnt, s4g, srg, ovf_cnt, ovf, E, NB, nbin, x, xb, 0);
            bucket_acc<false><<<NB, 256, 0, stream>>>(
                x, s4g, srg, bcnt, out, ovf_cnt, ovf, N);
            ovf_apply<false><<<64, 256, 0, stream>>>(x, ovf_cnt, ovf, out);
        }
    } else {
        (void)hipMemsetAsync(out, 0, (size_t)out_size * sizeof(float), stream);
        long long threads = (long long)E * 16;
        scatter_edges<<<(int)((threads + 255) / 256), 256, 0, stream>>>(
            x, ei, ew, out, E);
    }
}

// Round 9
// 163.621 us; speedup vs baseline: 1.1085x; 1.1037x over previous
//
#include <hip/hip_runtime.h>
#include <hip/hip_fp16.h>
#include <stdint.h>

// LightGCNConv: out[row] += x[col] * edge_weight[e]
// x:[N,64] f32, edge_index:[2,E] int32, edge_weight:[E] f32, out:[N,64] f32.
//
// Pipeline (v9 — TWO-LEVEL radix binning; run-length fix):
//  v8 post-mortem: single-pass binning to 1563 buckets gives sorted runs of
//  CHUNK/NB = 2.6 entries (~10B) -> still partial-line scatter (WRITE 62MB
//  vs 20MB useful, prep pinned at 52us, VALUBusy 3.8%). Fix = radix:
//  1) prep: chunk-sort 4096 edges into <=32 SUPERbuckets (4096 rows each).
//     Runs ~164 entries (1.3KB) -> full-line 8B-entry stores. LDS 32.5KB.
//  2) bin2: per superbucket-chunk: coalesced read, sort into 64 fine
//     buckets (64 rows). Runs ~64 entries (512B) -> coalesced seg2 stores.
//  3) bucket_acc: unchanged v8 structure (51.8us): seg2 -> LDS padded-CSR
//     -> per-wave register accumulation, 8-deep pipelined bf16 gathers ->
//     coalesced nontemporal out stores.

typedef unsigned long long ull;
typedef int   v4i __attribute__((ext_vector_type(4)));
typedef float v4f __attribute__((ext_vector_type(4)));
typedef unsigned char  uchar;

#define RB      64       // rows per fine bucket
#define CAP     1280     // entries per fine-bucket segment; mean 1024 (+8s)
#define CHUNK   4096     // edges per sort block (512 thr x 8)
#define EPT     8        // entries per thread
#define SLOTS   48       // padded-CSR slots per row (deg ~Poisson(16))
#define BPAD    16       // counter stride in ints (64B lines)
#define OVF_CAP 65536
#define NSBP    32       // max superbuckets (N <= 131072)
#define SBROWS  4096     // rows per superbucket

__device__ __forceinline__ unsigned short f2bf(float f) {
    union { float f; unsigned int u; } c;
    c.f = f;
    unsigned int lsb = (c.u >> 16) & 1u;
    c.u += 0x7fffu + lsb;
    return (unsigned short)(c.u >> 16);
}
__device__ __forceinline__ float bf2f(unsigned short u) {
    union { unsigned int u; float f; } c;
    c.u = ((unsigned int)u) << 16;
    return c.f;
}
__device__ __forceinline__ float unpack_w(unsigned v) {
    return __half2float(__ushort_as_half((unsigned short)((v & 0x7fffu) << 1)));
}

// ---------- pass 1: chunk -> superbucket sort | x->bf16 convert ----------
// entry fmt seg1: [hw:16 @48][row:17 @24][col:17 @0]
__global__ __launch_bounds__(512) void prep(
    const int* __restrict__ ei, const float* __restrict__ ew,
    int* __restrict__ bcnt1, ull* __restrict__ seg1, int cap1,
    int* __restrict__ ovf_cnt, int3* __restrict__ ovf, int E, int nbin,
    const float* __restrict__ x, unsigned short* __restrict__ xb, int n4)
{
    __shared__ int hist[NSBP];
    __shared__ int lstart[NSBP];
    __shared__ int gbase[NSBP];
    __shared__ ull sorted[CHUNK];     // 32 KB
    int t = threadIdx.x;

    if ((int)blockIdx.x >= nbin) {
        // ---- convert part: 4096 v4f per block ----
        int i0 = ((int)blockIdx.x - nbin) * 4096 + t;
#pragma unroll
        for (int k = 0; k < 8; ++k) {
            int i = i0 + k * 512;
            if (i < n4) {
                v4f v = ((const v4f*)x)[i];
                ushort4 o;
                o.x = f2bf(v.x); o.y = f2bf(v.y);
                o.z = f2bf(v.z); o.w = f2bf(v.w);
                ((ushort4*)xb)[i] = o;
            }
        }
        return;
    }

    if (t < NSBP) hist[t] = 0;
    __syncthreads();

    int e0   = blockIdx.x * CHUNK;
    int nval = E - e0; if (nval > CHUNK) nval = CHUNK;
    bool al4 = ((E & 3) == 0);

    int   rk[EPT];
    uchar sb[EPT];
    ull   cw[EPT];
    bool  vd[EPT];
#pragma unroll
    for (int j = 0; j < EPT / 4; ++j) {
        int eb = e0 + (j * 512 + t) * 4;
        v4i r4, c4; v4f w4;
        if (al4 && eb + 3 < E) {
            r4 = *(const v4i*)(ei + eb);
            c4 = *(const v4i*)(ei + E + eb);
            w4 = *(const v4f*)(ew + eb);
        } else {
#pragma unroll
            for (int u = 0; u < 4; ++u) {
                int e = eb + u;
                r4[u] = e < E ? ei[e] : 0;
                c4[u] = e < E ? ei[E + e] : 0;
                w4[u] = e < E ? ew[e] : 0.f;
            }
        }
#pragma unroll
        for (int u = 0; u < 4; ++u) {
            int idx = j * 4 + u;
            int e = eb + u;
            vd[idx] = e < E;
            int b = r4[u] >> 12;
            rk[idx] = vd[idx] ? atomicAdd(&hist[b], 1) : 0;   // LDS native
            sb[idx] = (uchar)b;
            unsigned hw = __half_as_ushort(__float2half(w4[u]));
            cw[idx] = ((ull)hw << 48) | ((ull)(unsigned)r4[u] << 24) |
                      (ull)(unsigned)c4[u];
        }
    }
    __syncthreads();

    // reservations + exclusive scan, single wave (t<32)
    if (t < 32) {
        int h = hist[t];
        gbase[t] = h ? atomicAdd(&bcnt1[t * BPAD], h) : 0;   // hides under scan
        int s = h;
#pragma unroll
        for (int off = 1; off < 32; off <<= 1) {
            int o = __shfl_up(s, off);
            if (t >= off) s += o;
        }
        lstart[t] = s - h;
    }
    __syncthreads();

    // place sorted in LDS
#pragma unroll
    for (int j = 0; j < EPT; ++j) {
        if (!vd[j]) continue;
        sorted[lstart[sb[j]] + rk[j]] = cw[j];
    }
    __syncthreads();

    // sweep store: runs ~CHUNK/NSB = 164 entries -> full-line stores
    for (int i = t; i < nval; i += 512) {
        ull e = sorted[i];
        int b = (int)((e >> 24) & 0x1FFFF) >> 12;
        int loc = gbase[b] + (i - lstart[b]);
        if (loc < cap1) {
            seg1[(size_t)b * cap1 + loc] = e;
        } else {
            int o = atomicAdd(ovf_cnt, 1);
            if (o < OVF_CAP)
                ovf[o] = make_int3((int)((e >> 24) & 0x1FFFF),
                                   (int)(e & 0x1FFFF),
                                   __float_as_int(__half2float(
                                       __ushort_as_half((unsigned short)(e >> 48)))));
        }
    }
}

// ---------- pass 2: superbucket chunk -> fine-bucket sort ----------
// seg2 entry fmt: [hw:16 @32][rl:6 @17][col:17 @0]
__global__ __launch_bounds__(512) void bin2(
    const ull* __restrict__ seg1, int cap1, const int* __restrict__ bcnt1,
    int* __restrict__ bcnt, ull* __restrict__ seg2,
    int* __restrict__ ovf_cnt, int3* __restrict__ ovf, int chpersb)
{
    __shared__ int hist[64];
    __shared__ int lstart[64];
    __shared__ int gbase[64];
    __shared__ ull sorted[CHUNK];     // 32 KB
    int t  = threadIdx.x;
    int sb = blockIdx.x / chpersb;
    int ch = blockIdx.x % chpersb;

    int cnt1 = bcnt1[sb * BPAD];
    if (cnt1 > cap1) cnt1 = cap1;
    int s0 = ch * CHUNK;
    int nval = cnt1 - s0;
    if (nval <= 0) return;
    if (nval > CHUNK) nval = CHUNK;

    if (t < 64) hist[t] = 0;
    __syncthreads();

    const ull* base = seg1 + (size_t)sb * cap1 + s0;

    int   rk[EPT];
    uchar fb[EPT];
    ull   cw[EPT];
    bool  vd[EPT];
#pragma unroll
    for (int j = 0; j < EPT; ++j) {
        int i = t + j * 512;                 // coalesced 8B reads
        vd[j] = i < nval;
        ull e = vd[j] ? base[i] : 0;
        int row = (int)((e >> 24) & 0x1FFFF);
        int f = (row >> 6) & 63;
        rk[j] = vd[j] ? atomicAdd(&hist[f], 1) : 0;   // LDS native
        fb[j] = (uchar)f;
        cw[j] = e;
    }
    __syncthreads();

    // reservations + exclusive scan, single wave (t<64)
    if (t < 64) {
        int h = hist[t];
        int fbg = sb * 64 + t;
        gbase[t] = h ? atomicAdd(&bcnt[fbg * BPAD], h) : 0;
        int s = h;
#pragma unroll
        for (int off = 1; off < 64; off <<= 1) {
            int o = __shfl_up(s, off);
            if (t >= off) s += o;
        }
        lstart[t] = s - h;
    }
    __syncthreads();

#pragma unroll
    for (int j = 0; j < EPT; ++j) {
        if (!vd[j]) continue;
        sorted[lstart[fb[j]] + rk[j]] = cw[j];
    }
    __syncthreads();

    // sweep store: runs ~CHUNK/64 = 64 entries (512B) -> coalesced
    for (int i = t; i < nval; i += 512) {
        ull e = sorted[i];
        int row = (int)((e >> 24) & 0x1FFFF);
        int f = (row >> 6) & 63;
        int loc = gbase[f] + (i - lstart[f]);
        int fbg = sb * 64 + f;
        if (loc < CAP) {
            ull hw = (e >> 48) & 0xFFFF;
            seg2[(size_t)fbg * CAP + loc] =
                (hw << 32) | ((ull)(unsigned)(row & 63) << 17) |
                (e & 0x1FFFF);
        } else {
            int o = atomicAdd(ovf_cnt, 1);
            if (o < OVF_CAP)
                ovf[o] = make_int3(row, (int)(e & 0x1FFFF),
                                   __float_as_int(__half2float(
                                       __ushort_as_half((unsigned short)(e >> 48)))));
        }
    }
}

// ---------- phase 3: seg2 -> LDS padded CSR -> register acc -> out ----
// 256 thr (4 waves), ~12.5 KB LDS, 8 blocks/CU cap, grid ~1563.
template <bool BF>
__global__ __launch_bounds__(256, 8) void bucket_acc(
    const void* __restrict__ xv, const ull* __restrict__ seg2,
    const int* __restrict__ bcnt, float* __restrict__ out,
    int* __restrict__ ovf_cnt, int3* __restrict__ ovf, int N)
{
    __shared__ int      cur[RB];
    __shared__ unsigned tile[RB * SLOTS];   // 12 KB packed col<<15|hw>>1
    int t = threadIdx.x;
    int g = blockIdx.x;
    if (t < RB) cur[t] = 0;
    __syncthreads();

    int c = bcnt[g * BPAD];
    if (c > CAP) c = CAP;
    const ull* b8 = seg2 + (size_t)g * CAP;

    // build LDS CSR: coalesced 8B reads, LDS cursor atomic, LDS write
    for (int i = t; i < c; i += 256) {
        ull e = b8[i];
        int rl = (int)((e >> 17) & 63);
        unsigned p4 = ((unsigned)(e & 0x1FFFF) << 15) |
                      ((unsigned)(e >> 33) & 0x7FFF);
        int pos = atomicAdd(&cur[rl], 1);          // native LDS int atomic
        if (pos < SLOTS) {
            tile[rl * SLOTS + pos] = p4;
        } else {
            int o = atomicAdd(ovf_cnt, 1);
            if (o < OVF_CAP)
                ovf[o] = make_int3(g * RB + rl, (int)(p4 >> 15),
                                   __float_as_int(unpack_w(p4)));
        }
    }
    __syncthreads();

    // register accumulation: each wave handles 16 rows, 8-deep gathers
    int wid  = t >> 6;
    int lane = t & 63;
    const unsigned short* xh = (const unsigned short*)xv;
    const float*          xf = (const float*)xv;

    for (int k = 0; k < 16; ++k) {
        int r   = wid * 16 + k;
        int row = g * RB + r;
        if (row >= N) break;
        int cc = cur[r];
        if (cc > SLOTS) cc = SLOTS;
        const unsigned* tb = &tile[r * SLOTS];

        float acc = 0.0f;
        int p = 0;
        for (; p + 8 <= cc; p += 8) {
            unsigned a[8]; float xr[8];
#pragma unroll
            for (int i = 0; i < 8; ++i) a[i] = tb[p + i];   // LDS broadcast
#pragma unroll
            for (int i = 0; i < 8; ++i) {
                size_t off = (((size_t)(a[i] >> 15)) << 6) + lane;
                xr[i] = BF ? bf2f(xh[off]) : xf[off];
            }
#pragma unroll
            for (int i = 0; i < 8; ++i)
                acc = fmaf(xr[i], unpack_w(a[i]), acc);
        }
        if (p < cc) {   // masked 8-group tail (cc >= 1 here)
            unsigned a[8]; float xr[8], w[8];
#pragma unroll
            for (int i = 0; i < 8; ++i) {
                int q = p + i;
                bool valid = q < cc;
                if (!valid) q = cc - 1;
                a[i] = tb[q];
                w[i] = valid ? unpack_w(a[i]) : 0.0f;
            }
#pragma unroll
            for (int i = 0; i < 8; ++i) {
                size_t off = (((size_t)(a[i] >> 15)) << 6) + lane;
                xr[i] = BF ? bf2f(xh[off]) : xf[off];
            }
#pragma unroll
            for (int i = 0; i < 8; ++i) acc = fmaf(xr[i], w[i], acc);
        }
        __builtin_nontemporal_store(acc, out + (((size_t)row) << 6) + lane);
    }
}

// ---------- overflow fixup (normally 0 edges) ----------
template <bool BF>
__global__ __launch_bounds__(256) void ovf_apply(
    const void* __restrict__ xv, const int* __restrict__ ovf_cnt,
    const int3* __restrict__ ovf, float* __restrict__ out)
{
    int n = *ovf_cnt;
    if (n > OVF_CAP) n = OVF_CAP;
    int wid  = (blockIdx.x * 256 + threadIdx.x) >> 6;
    int lane = threadIdx.x & 63;
    int nw   = gridDim.x * 4;
    for (int o = wid; o < n; o += nw) {
        int3 tt = ovf[o];
        float w = __int_as_float(tt.z);
        size_t off = (((size_t)tt.y) << 6) + lane;
        float x = BF ? bf2f(((const unsigned short*)xv)[off])
                     : ((const float*)xv)[off];
        atomicAdd(&out[(((size_t)tt.x) << 6) + lane], x * w);
    }
}

// ---------- fallback: direct atomic scatter ----------
__global__ __launch_bounds__(256) void scatter_edges(
    const float* __restrict__ x, const int* __restrict__ ei,
    const float* __restrict__ ew, float* __restrict__ out, int E)
{
    long long idx = (long long)blockIdx.x * 256 + threadIdx.x;
    int e = (int)(idx >> 4);
    if (e >= E) return;
    int j = (int)(idx & 15);
    int row = ei[e];
    int col = ei[E + e];
    float w = ew[e];
    v4f v = *(const v4f*)(x + (((size_t)col) << 6) + (j << 2));
    float* op = out + (((size_t)row) << 6) + (j << 2);
    atomicAdd(op + 0, v.x * w);
    atomicAdd(op + 1, v.y * w);
    atomicAdd(op + 2, v.z * w);
    atomicAdd(op + 3, v.w * w);
}

extern "C" void kernel_launch(void* const* d_in, const int* in_sizes, int n_in,
                              void* d_out, int out_size, void* d_ws, size_t ws_size,
                              hipStream_t stream) {
    const float* x  = (const float*)d_in[0];
    const int*   ei = (const int*)d_in[1];
    const float* ew = (const float*)d_in[2];
    float*       out = (float*)d_out;

    int E = in_sizes[2];
    int N = out_size / 64;
    int NB  = (N + RB - 1) / RB;
    int NSB = (N + SBROWS - 1) / SBROWS;

    long long mean1 = (long long)E * SBROWS / (N > 0 ? N : 1);
    int cap1 = (int)(mean1 + mean1 / 20 + CHUNK);
    cap1 = (cap1 + 1023) & ~1023;
    int chpersb = (cap1 + CHUNK - 1) / CHUNK;

    // ws (ints): bcnt1[32*BPAD] | bcnt[NB*BPAD] | ovf_cnt | pad |
    //            ovf[3*OVF] | xb[N*32] | seg1[NSB*cap1*2] | seg2[NB*CAP*2]
    size_t bcnt_base = (size_t)NSBP * BPAD;
    size_t ovfc_base = bcnt_base + (size_t)NB * BPAD;
    size_t ovf_base  = (ovfc_base + 1 + 3) & ~(size_t)3;
    size_t xb_base   = (ovf_base + 3 * (size_t)OVF_CAP + 3) & ~(size_t)3;
    size_t seg1_base = (xb_base + (size_t)N * 32 + 1) & ~(size_t)1;
    size_t seg2_base = seg1_base + (size_t)NSB * cap1 * 2;
    size_t need      = (seg2_base + (size_t)NB * CAP * 2) * 4;

    int nbin  = (E + CHUNK - 1) / CHUNK;
    int n4    = (N * 64) / 4;
    int nconv = (n4 + CHUNK - 1) / CHUNK;

    if (ws_size >= need && N <= (1 << 17)) {
        int* w32 = (int*)d_ws;
        int* bcnt1   = w32;
        int* bcnt    = w32 + bcnt_base;
        int* ovf_cnt = w32 + ovfc_base;
        int3* ovf    = (int3*)(w32 + ovf_base);
        unsigned short* xb = (unsigned short*)(w32 + xb_base);
        ull* seg1 = (ull*)(w32 + seg1_base);
        ull* seg2 = (ull*)(w32 + seg2_base);

        (void)hipMemsetAsync(w32, 0,
            (bcnt_base + (size_t)NB * BPAD + 2) * sizeof(int), stream);

        prep<<<nbin + nconv, 512, 0, stream>>>(
            ei, ew, bcnt1, seg1, cap1, ovf_cnt, ovf, E, nbin, x, xb, n4);
        bin2<<<NSB * chpersb, 512, 0, stream>>>(
            seg1, cap1, bcnt1, bcnt, seg2, ovf_cnt, ovf, chpersb);
        bucket_acc<true><<<NB, 256, 0, stream>>>(
            xb, seg2, bcnt, out, ovf_cnt, ovf, N);
        ovf_apply<true><<<64, 256, 0, stream>>>(xb, ovf_cnt, ovf, out);
    } else {
        (void)hipMemsetAsync(out, 0, (size_t)out_size * sizeof(float), stream);
        long long threads = (long long)E * 16;
        scatter_edges<<<(int)((threads + 255) / 256), 256, 0, stream>>>(
            x, ei, ew, out, E);
    }
}